// Round 3
// baseline (1227.269 us; speedup 1.0000x reference)
//
#include <hip/hip_runtime.h>
#include <math.h>

#define DIM 128
#define TR 32  // rows per fused-GEMM block

__global__ void fill_zero4(float4* p, int n4) {
    int i = blockIdx.x * blockDim.x + threadIdx.x;
    if (i < n4) p[i] = make_float4(0.f, 0.f, 0.f, 0.f);
}

__global__ void fill_zero(float* p, int n) {
    int i = blockIdx.x * blockDim.x + threadIdx.x;
    if (i < n) p[i] = 0.f;
}

// deg[col] += ew[e]   (edge_index arrives as int32: harness converts integer inputs)
__global__ void deg_kernel(const int* __restrict__ ei, const float* __restrict__ ew,
                           float* __restrict__ deg, int E) {
    int e = blockIdx.x * blockDim.x + threadIdx.x;
    if (e < E) {
        int col = ei[E + e];
        atomicAdd(&deg[col], ew[e]);
    }
}

// in-place deg -> dinv
__global__ void dinv_kernel(float* deg, int N) {
    int i = blockIdx.x * blockDim.x + threadIdx.x;
    if (i < N) {
        float d = deg[i];
        deg[i] = d > 0.f ? rsqrtf(d) : 0.f;
    }
}

// out[col] += (dinv[row]*ew*dinv[col]) * x[row]; 32 lanes/edge, float4 gather + 4 dword atomics
__global__ void scatter_kernel(const int* __restrict__ ei, const float* __restrict__ ew,
                               const float* __restrict__ dinv, const float* __restrict__ x,
                               float* __restrict__ out, int E) {
    int t = blockIdx.x * blockDim.x + threadIdx.x;
    int e = t >> 5;
    if (e >= E) return;
    int lane = t & 31;
    int row = ei[e];
    int col = ei[E + e];
    float w = dinv[row] * ew[e] * dinv[col];
    float4 v = *(const float4*)(x + (size_t)row * DIM + (lane << 2));
    float* dst = out + (size_t)col * DIM + (lane << 2);
    atomicAdd(dst + 0, v.x * w);
    atomicAdd(dst + 1, v.y * w);
    atomicAdd(dst + 2, v.z * w);
    atomicAdd(dst + 3, v.w * w);
}

// In-place fused: out = x + gelu(LN(out@W + b) * gamma + beta)
// block = 256 threads, 32 rows, 4x4 micro-tile; s-tile transposed in LDS (stride 36 -> 16B aligned).
// Each block fully reads its 32 rows into LDS before writing them back -> in-place safe (N%32==0).
__global__ __launch_bounds__(256) void gemm_ln_kernel(const float* __restrict__ x,
                                                      const float* __restrict__ W,
                                                      const float* __restrict__ b,
                                                      const float* __restrict__ gamma,
                                                      const float* __restrict__ beta,
                                                      float* __restrict__ out, int N) {
    __shared__ float sT[DIM][TR + 4];  // 18 KB
    const int tid = threadIdx.x;
    const int row0 = blockIdx.x * TR;

    // cooperative staged load: thread -> row tid/8, 16 consecutive cols
    {
        int r = tid >> 3;
        int c0 = (tid & 7) << 4;
        int rr = row0 + r; if (rr > N - 1) rr = N - 1;
        const float4* src = (const float4*)(out + (size_t)rr * DIM + c0);
#pragma unroll
        for (int i = 0; i < 4; ++i) {
            float4 v = src[i];
            int c = c0 + i * 4;
            sT[c + 0][r] = v.x; sT[c + 1][r] = v.y; sT[c + 2][r] = v.z; sT[c + 3][r] = v.w;
        }
    }
    __syncthreads();

    const int tx = tid & 31;   // output cols tx*4 .. tx*4+3
    const int ty = tid >> 5;   // rows ty*4 .. ty*4+3
    float acc[4][4] = {};
    const float4* Wv = (const float4*)W;
#pragma unroll 4
    for (int k = 0; k < DIM; ++k) {
        float4 wv = Wv[k * 32 + tx];                      // W[k][4tx..4tx+3]
        float4 a  = *(const float4*)(&sT[k][ty * 4]);     // s[r0..r3][k]
        acc[0][0] += a.x * wv.x; acc[0][1] += a.x * wv.y; acc[0][2] += a.x * wv.z; acc[0][3] += a.x * wv.w;
        acc[1][0] += a.y * wv.x; acc[1][1] += a.y * wv.y; acc[1][2] += a.y * wv.z; acc[1][3] += a.y * wv.w;
        acc[2][0] += a.z * wv.x; acc[2][1] += a.z * wv.y; acc[2][2] += a.z * wv.z; acc[2][3] += a.z * wv.w;
        acc[3][0] += a.w * wv.x; acc[3][1] += a.w * wv.y; acc[3][2] += a.w * wv.z; acc[3][3] += a.w * wv.w;
    }

    // + bias
    float4 b4 = ((const float4*)b)[tx];
#pragma unroll
    for (int i = 0; i < 4; ++i) {
        acc[i][0] += b4.x; acc[i][1] += b4.y; acc[i][2] += b4.z; acc[i][3] += b4.w;
    }

    // LayerNorm per row: reduce across the 32 lanes sharing this ty (xor offsets <32 stay in half-wave)
    float4 g4  = ((const float4*)gamma)[tx];
    float4 be4 = ((const float4*)beta)[tx];
#pragma unroll
    for (int i = 0; i < 4; ++i) {
        float s  = acc[i][0] + acc[i][1] + acc[i][2] + acc[i][3];
        float sq = acc[i][0]*acc[i][0] + acc[i][1]*acc[i][1] + acc[i][2]*acc[i][2] + acc[i][3]*acc[i][3];
#pragma unroll
        for (int off = 16; off > 0; off >>= 1) {
            s  += __shfl_xor(s, off);
            sq += __shfl_xor(sq, off);
        }
        float mu   = s * (1.0f / DIM);
        float var  = sq * (1.0f / DIM) - mu * mu;
        float rstd = rsqrtf(var + 1e-5f);

        int r = row0 + ty * 4 + i;
        if (r < N) {
            float4 xr = *(const float4*)(x + (size_t)r * DIM + tx * 4);
            float lg[4] = {g4.x, g4.y, g4.z, g4.w};
            float lb[4] = {be4.x, be4.y, be4.z, be4.w};
            float lx[4] = {xr.x, xr.y, xr.z, xr.w};
            float o[4];
#pragma unroll
            for (int c = 0; c < 4; ++c) {
                float l = (acc[i][c] - mu) * rstd * lg[c] + lb[c];
                float g = 0.5f * l * (1.0f + erff(l * 0.70710678118654752f));
                o[c] = lx[c] + g;
            }
            *(float4*)(out + (size_t)r * DIM + tx * 4) = make_float4(o[0], o[1], o[2], o[3]);
        }
    }
}

extern "C" void kernel_launch(void* const* d_in, const int* in_sizes, int n_in,
                              void* d_out, int out_size, void* d_ws, size_t ws_size,
                              hipStream_t stream) {
    const float* x     = (const float*)d_in[0];
    const int*   ei    = (const int*)d_in[1];    // [2, E] int32 (harness converts int64 -> int32)
    const float* ew    = (const float*)d_in[2];
    const float* W     = (const float*)d_in[3];
    const float* b     = (const float*)d_in[4];
    const float* gamma = (const float*)d_in[5];
    const float* beta  = (const float*)d_in[6];
    const int N = in_sizes[0] / DIM;
    const int E = in_sizes[2];
    float* out = (float*)d_out;

    float* deg = (float*)d_ws;  // N floats (400 KB)

    int n4 = N * DIM / 4;
    fill_zero4<<<(n4 + 255) / 256, 256, 0, stream>>>((float4*)out, n4);
    fill_zero <<<(N + 255) / 256, 256, 0, stream>>>(deg, N);

    deg_kernel <<<(E + 255) / 256, 256, 0, stream>>>(ei, ew, deg, E);
    dinv_kernel<<<(N + 255) / 256, 256, 0, stream>>>(deg, N);

    long long sthreads = (long long)E * 32;
    scatter_kernel<<<(int)((sthreads + 255) / 256), 256, 0, stream>>>(ei, ew, deg, x, out, E);

    gemm_ln_kernel<<<N / TR + (N % TR != 0), 256, 0, stream>>>(x, W, b, gamma, beta, out, N);
}

// Round 4
// 336.465 us; speedup vs baseline: 3.6475x; 3.6475x over previous
//
#include <hip/hip_runtime.h>
#include <math.h>

#define DIM 128
#define TR 32  // rows per fused-GEMM block

__global__ void fill_zero(float* p, int n) {
    int i = blockIdx.x * blockDim.x + threadIdx.x;
    if (i < n) p[i] = 0.f;
}

__global__ void fill_zero4(float4* p, int n4) {
    int i = blockIdx.x * blockDim.x + threadIdx.x;
    if (i < n4) p[i] = make_float4(0.f, 0.f, 0.f, 0.f);
}

// cnt[col]++ ; deg[col] += ew[e]
__global__ void count_deg_kernel(const int* __restrict__ ei, const float* __restrict__ ew,
                                 int* __restrict__ cnt, float* __restrict__ deg, int E) {
    int e = blockIdx.x * blockDim.x + threadIdx.x;
    if (e < E) {
        int col = ei[E + e];
        atomicAdd(&cnt[col], 1);
        atomicAdd(&deg[col], ew[e]);
    }
}

// in-place deg -> dinv
__global__ void dinv_kernel(float* deg, int N) {
    int i = blockIdx.x * blockDim.x + threadIdx.x;
    if (i < N) {
        float d = deg[i];
        deg[i] = d > 0.f ? rsqrtf(d) : 0.f;
    }
}

// per-block exclusive scan of cnt (256/block) -> start_local, blockSums
__global__ __launch_bounds__(256) void scan1_kernel(const int* __restrict__ cnt,
                                                    int* __restrict__ start_local,
                                                    int* __restrict__ blockSums, int N) {
    __shared__ int s[256];
    int t = threadIdx.x;
    int i = blockIdx.x * 256 + t;
    int c = (i < N) ? cnt[i] : 0;
    s[t] = c;
    __syncthreads();
#pragma unroll
    for (int off = 1; off < 256; off <<= 1) {
        int v = (t >= off) ? s[t - off] : 0;
        __syncthreads();
        s[t] += v;
        __syncthreads();
    }
    if (i < N) start_local[i] = s[t] - c;      // exclusive
    if (t == 255) blockSums[blockIdx.x] = s[t]; // block total
}

// single-block exclusive scan of blockSums (nb <= 512)
__global__ __launch_bounds__(512) void scan2_kernel(int* __restrict__ blockSums, int nb) {
    __shared__ int s[512];
    int t = threadIdx.x;
    int c = (t < nb) ? blockSums[t] : 0;
    s[t] = c;
    __syncthreads();
#pragma unroll
    for (int off = 1; off < 512; off <<= 1) {
        int v = (t >= off) ? s[t - off] : 0;
        __syncthreads();
        s[t] += v;
        __syncthreads();
    }
    if (t < nb) blockSums[t] = s[t] - c;  // exclusive
}

// row_start[i] = start_local[i] + blockSums[i/256]; cursor[i] = same
__global__ void scan3_kernel(const int* __restrict__ start_local, const int* __restrict__ blockSums,
                             int* __restrict__ row_start, int* __restrict__ cursor, int N) {
    int i = blockIdx.x * blockDim.x + threadIdx.x;
    if (i < N) {
        int rs = start_local[i] + blockSums[i >> 8];
        row_start[i] = rs;
        cursor[i] = rs;
    }
}

// CSR fill: p = cursor[col]++; csr_src[p] = row; csr_w[p] = dinv[row]*ew*dinv[col]
__global__ void csr_fill_kernel(const int* __restrict__ ei, const float* __restrict__ ew,
                                const float* __restrict__ dinv, int* __restrict__ cursor,
                                int* __restrict__ csr_src, float* __restrict__ csr_w, int E) {
    int e = blockIdx.x * blockDim.x + threadIdx.x;
    if (e < E) {
        int row = ei[e];
        int col = ei[E + e];
        int p = atomicAdd(&cursor[col], 1);
        csr_src[p] = row;
        csr_w[p] = dinv[row] * ew[e] * dinv[col];
    }
}

// gather: 32 lanes per node, float4 per lane; out[node] = sum_j w_j * x[src_j]
// seg_end = cursor (post-fill cursor == segment end). No atomics, no pre-zeroing of out.
__global__ __launch_bounds__(256) void gather_kernel(const int* __restrict__ csr_src,
                                                     const float* __restrict__ csr_w,
                                                     const int* __restrict__ row_start,
                                                     const int* __restrict__ seg_end,
                                                     const float* __restrict__ x,
                                                     float* __restrict__ out, int N) {
    int t = blockIdx.x * blockDim.x + threadIdx.x;
    int node = t >> 5;
    if (node >= N) return;
    int lane = t & 31;
    int s = row_start[node];
    int e = seg_end[node];
    const float4* xv = (const float4*)x;
    float4 acc = make_float4(0.f, 0.f, 0.f, 0.f);
    for (int j = s; j < e; ++j) {
        int src = csr_src[j];       // broadcast across the 32-lane group
        float w = csr_w[j];
        float4 v = xv[(size_t)src * 32 + lane];
        acc.x += w * v.x; acc.y += w * v.y; acc.z += w * v.z; acc.w += w * v.w;
    }
    ((float4*)out)[(size_t)node * 32 + lane] = acc;
}

// --- fallback path (atomic scatter) if workspace is too small ---
__global__ void deg_kernel(const int* __restrict__ ei, const float* __restrict__ ew,
                           float* __restrict__ deg, int E) {
    int e = blockIdx.x * blockDim.x + threadIdx.x;
    if (e < E) atomicAdd(&deg[ei[E + e]], ew[e]);
}

__global__ void scatter_kernel(const int* __restrict__ ei, const float* __restrict__ ew,
                               const float* __restrict__ dinv, const float* __restrict__ x,
                               float* __restrict__ out, int E) {
    int t = blockIdx.x * blockDim.x + threadIdx.x;
    int e = t >> 5;
    if (e >= E) return;
    int lane = t & 31;
    int row = ei[e];
    int col = ei[E + e];
    float w = dinv[row] * ew[e] * dinv[col];
    float4 v = *(const float4*)(x + (size_t)row * DIM + (lane << 2));
    float* dst = out + (size_t)col * DIM + (lane << 2);
    atomicAdd(dst + 0, v.x * w);
    atomicAdd(dst + 1, v.y * w);
    atomicAdd(dst + 2, v.z * w);
    atomicAdd(dst + 3, v.w * w);
}

// In-place fused: out = x + gelu(LN(out@W + b) * gamma + beta)
// block = 256 threads, 32 rows, 4x4 micro-tile; s-tile transposed in LDS (stride 36 -> 16B aligned).
__global__ __launch_bounds__(256) void gemm_ln_kernel(const float* __restrict__ x,
                                                      const float* __restrict__ W,
                                                      const float* __restrict__ b,
                                                      const float* __restrict__ gamma,
                                                      const float* __restrict__ beta,
                                                      float* __restrict__ out, int N) {
    __shared__ float sT[DIM][TR + 4];
    const int tid = threadIdx.x;
    const int row0 = blockIdx.x * TR;

    {
        int r = tid >> 3;
        int c0 = (tid & 7) << 4;
        int rr = row0 + r; if (rr > N - 1) rr = N - 1;
        const float4* src = (const float4*)(out + (size_t)rr * DIM + c0);
#pragma unroll
        for (int i = 0; i < 4; ++i) {
            float4 v = src[i];
            int c = c0 + i * 4;
            sT[c + 0][r] = v.x; sT[c + 1][r] = v.y; sT[c + 2][r] = v.z; sT[c + 3][r] = v.w;
        }
    }
    __syncthreads();

    const int tx = tid & 31;
    const int ty = tid >> 5;
    float acc[4][4] = {};
    const float4* Wv = (const float4*)W;
#pragma unroll 4
    for (int k = 0; k < DIM; ++k) {
        float4 wv = Wv[k * 32 + tx];
        float4 a  = *(const float4*)(&sT[k][ty * 4]);
        acc[0][0] += a.x * wv.x; acc[0][1] += a.x * wv.y; acc[0][2] += a.x * wv.z; acc[0][3] += a.x * wv.w;
        acc[1][0] += a.y * wv.x; acc[1][1] += a.y * wv.y; acc[1][2] += a.y * wv.z; acc[1][3] += a.y * wv.w;
        acc[2][0] += a.z * wv.x; acc[2][1] += a.z * wv.y; acc[2][2] += a.z * wv.z; acc[2][3] += a.z * wv.w;
        acc[3][0] += a.w * wv.x; acc[3][1] += a.w * wv.y; acc[3][2] += a.w * wv.z; acc[3][3] += a.w * wv.w;
    }

    float4 b4 = ((const float4*)b)[tx];
#pragma unroll
    for (int i = 0; i < 4; ++i) {
        acc[i][0] += b4.x; acc[i][1] += b4.y; acc[i][2] += b4.z; acc[i][3] += b4.w;
    }

    float4 g4  = ((const float4*)gamma)[tx];
    float4 be4 = ((const float4*)beta)[tx];
#pragma unroll
    for (int i = 0; i < 4; ++i) {
        float s  = acc[i][0] + acc[i][1] + acc[i][2] + acc[i][3];
        float sq = acc[i][0]*acc[i][0] + acc[i][1]*acc[i][1] + acc[i][2]*acc[i][2] + acc[i][3]*acc[i][3];
#pragma unroll
        for (int off = 16; off > 0; off >>= 1) {
            s  += __shfl_xor(s, off);
            sq += __shfl_xor(sq, off);
        }
        float mu   = s * (1.0f / DIM);
        float var  = sq * (1.0f / DIM) - mu * mu;
        float rstd = rsqrtf(var + 1e-5f);

        int r = row0 + ty * 4 + i;
        if (r < N) {
            float4 xr = *(const float4*)(x + (size_t)r * DIM + tx * 4);
            float lg[4] = {g4.x, g4.y, g4.z, g4.w};
            float lb[4] = {be4.x, be4.y, be4.z, be4.w};
            float lx[4] = {xr.x, xr.y, xr.z, xr.w};
            float o[4];
#pragma unroll
            for (int c = 0; c < 4; ++c) {
                float l = (acc[i][c] - mu) * rstd * lg[c] + lb[c];
                float g = 0.5f * l * (1.0f + erff(l * 0.70710678118654752f));
                o[c] = lx[c] + g;
            }
            *(float4*)(out + (size_t)r * DIM + tx * 4) = make_float4(o[0], o[1], o[2], o[3]);
        }
    }
}

extern "C" void kernel_launch(void* const* d_in, const int* in_sizes, int n_in,
                              void* d_out, int out_size, void* d_ws, size_t ws_size,
                              hipStream_t stream) {
    const float* x     = (const float*)d_in[0];
    const int*   ei    = (const int*)d_in[1];    // [2, E] int32
    const float* ew    = (const float*)d_in[2];
    const float* W     = (const float*)d_in[3];
    const float* b     = (const float*)d_in[4];
    const float* gamma = (const float*)d_in[5];
    const float* beta  = (const float*)d_in[6];
    const int N = in_sizes[0] / DIM;
    const int E = in_sizes[2];
    float* out = (float*)d_out;

    const int nb = (N + 255) / 256;

    // workspace layout (words): deg[N] | cnt[N] | start_local[N] | blockSums[512] | row_start[N] | cursor[N] | csr_src[E] | csr_w[E]
    size_t ws_need = ((size_t)5 * N + 512 + (size_t)2 * E) * sizeof(float);

    if (ws_size >= ws_need && nb <= 512) {
        float* deg         = (float*)d_ws;
        int*   cnt         = (int*)(deg + N);
        int*   start_local = cnt + N;
        int*   blockSums   = start_local + N;
        int*   row_start   = blockSums + 512;
        int*   cursor      = row_start + N;
        int*   csr_src     = cursor + N;
        float* csr_w       = (float*)(csr_src + E);

        fill_zero<<<(2 * N + 255) / 256, 256, 0, stream>>>(deg, 2 * N);  // zeros deg + cnt
        count_deg_kernel<<<(E + 255) / 256, 256, 0, stream>>>(ei, ew, cnt, deg, E);
        dinv_kernel<<<nb, 256, 0, stream>>>(deg, N);
        scan1_kernel<<<nb, 256, 0, stream>>>(cnt, start_local, blockSums, N);
        scan2_kernel<<<1, 512, 0, stream>>>(blockSums, nb);
        scan3_kernel<<<nb, 256, 0, stream>>>(start_local, blockSums, row_start, cursor, N);
        csr_fill_kernel<<<(E + 255) / 256, 256, 0, stream>>>(ei, ew, deg, cursor, csr_src, csr_w, E);

        long long gthreads = (long long)N * 32;
        gather_kernel<<<(int)((gthreads + 255) / 256), 256, 0, stream>>>(
            csr_src, csr_w, row_start, cursor, x, out, N);
    } else {
        // fallback: atomic scatter (needs only N floats of ws)
        float* deg = (float*)d_ws;
        int n4 = N * DIM / 4;
        fill_zero4<<<(n4 + 255) / 256, 256, 0, stream>>>((float4*)out, n4);
        fill_zero<<<nb, 256, 0, stream>>>(deg, N);
        deg_kernel<<<(E + 255) / 256, 256, 0, stream>>>(ei, ew, deg, E);
        dinv_kernel<<<nb, 256, 0, stream>>>(deg, N);
        long long sthreads = (long long)E * 32;
        scatter_kernel<<<(int)((sthreads + 255) / 256), 256, 0, stream>>>(ei, ew, deg, x, out, E);
    }

    gemm_ln_kernel<<<N / TR + (N % TR != 0), 256, 0, stream>>>(x, W, b, gamma, beta, out, N);
}

// Round 5
// 308.793 us; speedup vs baseline: 3.9744x; 1.0896x over previous
//
#include <hip/hip_runtime.h>
#include <math.h>

#define DIM 128
#define TR 32  // nodes per fused block

__global__ void fill_zero(float* p, int n) {
    int i = blockIdx.x * blockDim.x + threadIdx.x;
    if (i < n) p[i] = 0.f;
}

__global__ void fill_zero4(float4* p, int n4) {
    int i = blockIdx.x * blockDim.x + threadIdx.x;
    if (i < n4) p[i] = make_float4(0.f, 0.f, 0.f, 0.f);
}

// cnt[col]++ ; deg[col] += ew[e]
__global__ void count_deg_kernel(const int* __restrict__ ei, const float* __restrict__ ew,
                                 int* __restrict__ cnt, float* __restrict__ deg, int E) {
    int e = blockIdx.x * blockDim.x + threadIdx.x;
    if (e < E) {
        int col = ei[E + e];
        atomicAdd(&cnt[col], 1);
        atomicAdd(&deg[col], ew[e]);
    }
}

// per-block exclusive scan of cnt (256/block) -> start_local, blockSums
__global__ __launch_bounds__(256) void scan1_kernel(const int* __restrict__ cnt,
                                                    int* __restrict__ start_local,
                                                    int* __restrict__ blockSums, int N) {
    __shared__ int s[256];
    int t = threadIdx.x;
    int i = blockIdx.x * 256 + t;
    int c = (i < N) ? cnt[i] : 0;
    s[t] = c;
    __syncthreads();
#pragma unroll
    for (int off = 1; off < 256; off <<= 1) {
        int v = (t >= off) ? s[t - off] : 0;
        __syncthreads();
        s[t] += v;
        __syncthreads();
    }
    if (i < N) start_local[i] = s[t] - c;
    if (t == 255) blockSums[blockIdx.x] = s[t];
}

// single-block exclusive scan of blockSums (nb <= 512)
__global__ __launch_bounds__(512) void scan2_kernel(int* __restrict__ blockSums, int nb) {
    __shared__ int s[512];
    int t = threadIdx.x;
    int c = (t < nb) ? blockSums[t] : 0;
    s[t] = c;
    __syncthreads();
#pragma unroll
    for (int off = 1; off < 512; off <<= 1) {
        int v = (t >= off) ? s[t - off] : 0;
        __syncthreads();
        s[t] += v;
        __syncthreads();
    }
    if (t < nb) blockSums[t] = s[t] - c;
}

// row_start[i] = start_local[i] + blockSums[i/256]; cursor[i] = same; deg -> dinv (fused)
__global__ void scan3_kernel(const int* __restrict__ start_local, const int* __restrict__ blockSums,
                             int* __restrict__ row_start, int* __restrict__ cursor,
                             float* __restrict__ deg, int N) {
    int i = blockIdx.x * blockDim.x + threadIdx.x;
    if (i < N) {
        int rs = start_local[i] + blockSums[i >> 8];
        row_start[i] = rs;
        cursor[i] = rs;
        float d = deg[i];
        deg[i] = d > 0.f ? rsqrtf(d) : 0.f;
    }
}

// CSR fill (packed 8B): p = cursor[col]++; csr[p] = {row, bits(dinv[row]*ew*dinv[col])}
__global__ void csr_fill_kernel(const int* __restrict__ ei, const float* __restrict__ ew,
                                const float* __restrict__ dinv, int* __restrict__ cursor,
                                int2* __restrict__ csr, int E) {
    int e = blockIdx.x * blockDim.x + threadIdx.x;
    if (e < E) {
        int row = ei[e];
        int col = ei[E + e];
        int p = atomicAdd(&cursor[col], 1);
        float w = dinv[row] * ew[e] * dinv[col];
        csr[p] = make_int2(row, __float_as_int(w));
    }
}

// Fused: gather agg rows into LDS, then out = x + gelu(LN(agg@W + b)*gamma + beta).
// 256 threads = 8 groups of 32 lanes; each group gathers 4 nodes (float4/lane, coalesced
// LDS float4 writes, row-major stride DIM+4). GEMM: 4x4 micro-tile, A via broadcast
// ds_read_b32 (2 addrs/wave = free), W streamed from global (64 KB, L1-resident).
__global__ __launch_bounds__(256) void gather_gemm_ln_kernel(
        const int2* __restrict__ csr, const int* __restrict__ row_start,
        const int* __restrict__ seg_end, const float* __restrict__ x,
        const float* __restrict__ W, const float* __restrict__ b,
        const float* __restrict__ gamma, const float* __restrict__ beta,
        float* __restrict__ out, int N) {
    __shared__ float sS[TR][DIM + 4];  // 16.5 KB, stride 132 floats (16B multiple)
    const int tid  = threadIdx.x;
    const int lane = tid & 31;
    const int grp  = tid >> 5;         // 0..7
    const int row0 = blockIdx.x * TR;

    // ---- Phase A: gather 4 nodes per 32-lane group ----
    const float4* xv = (const float4*)x;
#pragma unroll
    for (int q = 0; q < 4; ++q) {
        int r = grp * 4 + q;
        int node = row0 + r;
        float4 acc = make_float4(0.f, 0.f, 0.f, 0.f);
        if (node < N) {
            int s = row_start[node];
            int e = seg_end[node];
            for (int j = s; j < e; ++j) {
                int2 pk = csr[j];                       // broadcast within group
                float w  = __int_as_float(pk.y);
                float4 v = xv[(size_t)pk.x * 32 + lane];
                acc.x += w * v.x; acc.y += w * v.y; acc.z += w * v.z; acc.w += w * v.w;
            }
        }
        *(float4*)(&sS[r][lane * 4]) = acc;             // coalesced, conflict-free
    }
    __syncthreads();

    // ---- Phase B: 32x128 @ 128x128 GEMM + bias + LN + GELU + residual ----
    const int tx  = lane;        // output cols tx*4..tx*4+3
    const int ty4 = grp * 4;     // output rows ty4..ty4+3
    float acc[4][4] = {};
    const float4* Wv = (const float4*)W;
#pragma unroll 4
    for (int k = 0; k < DIM; ++k) {
        float4 wv = Wv[k * 32 + tx];     // W[k][4tx..4tx+3]
        float a0 = sS[ty4 + 0][k];
        float a1 = sS[ty4 + 1][k];
        float a2 = sS[ty4 + 2][k];
        float a3 = sS[ty4 + 3][k];
        acc[0][0] += a0 * wv.x; acc[0][1] += a0 * wv.y; acc[0][2] += a0 * wv.z; acc[0][3] += a0 * wv.w;
        acc[1][0] += a1 * wv.x; acc[1][1] += a1 * wv.y; acc[1][2] += a1 * wv.z; acc[1][3] += a1 * wv.w;
        acc[2][0] += a2 * wv.x; acc[2][1] += a2 * wv.y; acc[2][2] += a2 * wv.z; acc[2][3] += a2 * wv.w;
        acc[3][0] += a3 * wv.x; acc[3][1] += a3 * wv.y; acc[3][2] += a3 * wv.z; acc[3][3] += a3 * wv.w;
    }

    float4 b4 = ((const float4*)b)[tx];
#pragma unroll
    for (int i = 0; i < 4; ++i) {
        acc[i][0] += b4.x; acc[i][1] += b4.y; acc[i][2] += b4.z; acc[i][3] += b4.w;
    }

    float4 g4  = ((const float4*)gamma)[tx];
    float4 be4 = ((const float4*)beta)[tx];
#pragma unroll
    for (int i = 0; i < 4; ++i) {
        float s  = acc[i][0] + acc[i][1] + acc[i][2] + acc[i][3];
        float sq = acc[i][0]*acc[i][0] + acc[i][1]*acc[i][1] + acc[i][2]*acc[i][2] + acc[i][3]*acc[i][3];
#pragma unroll
        for (int off = 16; off > 0; off >>= 1) {   // reduce across half-wave (same ty)
            s  += __shfl_xor(s, off);
            sq += __shfl_xor(sq, off);
        }
        float mu   = s * (1.0f / DIM);
        float var  = sq * (1.0f / DIM) - mu * mu;
        float rstd = rsqrtf(var + 1e-5f);

        int r = row0 + ty4 + i;
        if (r < N) {
            float4 xr = *(const float4*)(x + (size_t)r * DIM + tx * 4);
            float lg[4] = {g4.x, g4.y, g4.z, g4.w};
            float lb[4] = {be4.x, be4.y, be4.z, be4.w};
            float lx[4] = {xr.x, xr.y, xr.z, xr.w};
            float o[4];
#pragma unroll
            for (int c = 0; c < 4; ++c) {
                float l = (acc[i][c] - mu) * rstd * lg[c] + lb[c];
                float g = 0.5f * l * (1.0f + erff(l * 0.70710678118654752f));
                o[c] = lx[c] + g;
            }
            *(float4*)(out + (size_t)r * DIM + tx * 4) = make_float4(o[0], o[1], o[2], o[3]);
        }
    }
}

// ---------------- fallback path (small workspace): atomic scatter ----------------
__global__ void deg_kernel(const int* __restrict__ ei, const float* __restrict__ ew,
                           float* __restrict__ deg, int E) {
    int e = blockIdx.x * blockDim.x + threadIdx.x;
    if (e < E) atomicAdd(&deg[ei[E + e]], ew[e]);
}

__global__ void dinv_kernel(float* deg, int N) {
    int i = blockIdx.x * blockDim.x + threadIdx.x;
    if (i < N) {
        float d = deg[i];
        deg[i] = d > 0.f ? rsqrtf(d) : 0.f;
    }
}

__global__ void scatter_kernel(const int* __restrict__ ei, const float* __restrict__ ew,
                               const float* __restrict__ dinv, const float* __restrict__ x,
                               float* __restrict__ out, int E) {
    int t = blockIdx.x * blockDim.x + threadIdx.x;
    int e = t >> 5;
    if (e >= E) return;
    int lane = t & 31;
    int row = ei[e];
    int col = ei[E + e];
    float w = dinv[row] * ew[e] * dinv[col];
    float4 v = *(const float4*)(x + (size_t)row * DIM + (lane << 2));
    float* dst = out + (size_t)col * DIM + (lane << 2);
    atomicAdd(dst + 0, v.x * w);
    atomicAdd(dst + 1, v.y * w);
    atomicAdd(dst + 2, v.z * w);
    atomicAdd(dst + 3, v.w * w);
}

__global__ __launch_bounds__(256) void gemm_ln_kernel(const float* __restrict__ x,
                                                      const float* __restrict__ W,
                                                      const float* __restrict__ b,
                                                      const float* __restrict__ gamma,
                                                      const float* __restrict__ beta,
                                                      float* __restrict__ out, int N) {
    __shared__ float sT[DIM][TR + 4];
    const int tid = threadIdx.x;
    const int row0 = blockIdx.x * TR;
    {
        int r = tid >> 3;
        int c0 = (tid & 7) << 4;
        int rr = row0 + r; if (rr > N - 1) rr = N - 1;
        const float4* src = (const float4*)(out + (size_t)rr * DIM + c0);
#pragma unroll
        for (int i = 0; i < 4; ++i) {
            float4 v = src[i];
            int c = c0 + i * 4;
            sT[c + 0][r] = v.x; sT[c + 1][r] = v.y; sT[c + 2][r] = v.z; sT[c + 3][r] = v.w;
        }
    }
    __syncthreads();
    const int tx = tid & 31;
    const int ty = tid >> 5;
    float acc[4][4] = {};
    const float4* Wv = (const float4*)W;
#pragma unroll 4
    for (int k = 0; k < DIM; ++k) {
        float4 wv = Wv[k * 32 + tx];
        float4 a  = *(const float4*)(&sT[k][ty * 4]);
        acc[0][0] += a.x * wv.x; acc[0][1] += a.x * wv.y; acc[0][2] += a.x * wv.z; acc[0][3] += a.x * wv.w;
        acc[1][0] += a.y * wv.x; acc[1][1] += a.y * wv.y; acc[1][2] += a.y * wv.z; acc[1][3] += a.y * wv.w;
        acc[2][0] += a.z * wv.x; acc[2][1] += a.z * wv.y; acc[2][2] += a.z * wv.z; acc[2][3] += a.z * wv.w;
        acc[3][0] += a.w * wv.x; acc[3][1] += a.w * wv.y; acc[3][2] += a.w * wv.z; acc[3][3] += a.w * wv.w;
    }
    float4 b4 = ((const float4*)b)[tx];
#pragma unroll
    for (int i = 0; i < 4; ++i) {
        acc[i][0] += b4.x; acc[i][1] += b4.y; acc[i][2] += b4.z; acc[i][3] += b4.w;
    }
    float4 g4  = ((const float4*)gamma)[tx];
    float4 be4 = ((const float4*)beta)[tx];
#pragma unroll
    for (int i = 0; i < 4; ++i) {
        float s  = acc[i][0] + acc[i][1] + acc[i][2] + acc[i][3];
        float sq = acc[i][0]*acc[i][0] + acc[i][1]*acc[i][1] + acc[i][2]*acc[i][2] + acc[i][3]*acc[i][3];
#pragma unroll
        for (int off = 16; off > 0; off >>= 1) {
            s  += __shfl_xor(s, off);
            sq += __shfl_xor(sq, off);
        }
        float mu   = s * (1.0f / DIM);
        float var  = sq * (1.0f / DIM) - mu * mu;
        float rstd = rsqrtf(var + 1e-5f);
        int r = row0 + ty * 4 + i;
        if (r < N) {
            float4 xr = *(const float4*)(x + (size_t)r * DIM + tx * 4);
            float lg[4] = {g4.x, g4.y, g4.z, g4.w};
            float lb[4] = {be4.x, be4.y, be4.z, be4.w};
            float lx[4] = {xr.x, xr.y, xr.z, xr.w};
            float o[4];
#pragma unroll
            for (int c = 0; c < 4; ++c) {
                float l = (acc[i][c] - mu) * rstd * lg[c] + lb[c];
                float g = 0.5f * l * (1.0f + erff(l * 0.70710678118654752f));
                o[c] = lx[c] + g;
            }
            *(float4*)(out + (size_t)r * DIM + tx * 4) = make_float4(o[0], o[1], o[2], o[3]);
        }
    }
}

extern "C" void kernel_launch(void* const* d_in, const int* in_sizes, int n_in,
                              void* d_out, int out_size, void* d_ws, size_t ws_size,
                              hipStream_t stream) {
    const float* x     = (const float*)d_in[0];
    const int*   ei    = (const int*)d_in[1];    // [2, E] int32
    const float* ew    = (const float*)d_in[2];
    const float* W     = (const float*)d_in[3];
    const float* b     = (const float*)d_in[4];
    const float* gamma = (const float*)d_in[5];
    const float* beta  = (const float*)d_in[6];
    const int N = in_sizes[0] / DIM;
    const int E = in_sizes[2];
    float* out = (float*)d_out;

    const int nb = (N + 255) / 256;

    // ws words: deg[N] | cnt[N] | start_local[N] | blockSums[512] | row_start[N] | cursor[N] | pad | csr int2[E]
    size_t hdr_words = (size_t)5 * N + 512;
    hdr_words = (hdr_words + 1) & ~(size_t)1;  // 8B-align csr
    size_t ws_need = (hdr_words + (size_t)2 * E) * sizeof(float);

    if (ws_size >= ws_need && nb <= 512) {
        float* deg         = (float*)d_ws;
        int*   cnt         = (int*)(deg + N);
        int*   start_local = cnt + N;
        int*   blockSums   = start_local + N;
        int*   row_start   = blockSums + 512;
        int*   cursor      = row_start + N;
        int2*  csr         = (int2*)((float*)d_ws + hdr_words);

        fill_zero<<<(2 * N + 255) / 256, 256, 0, stream>>>(deg, 2 * N);  // deg + cnt
        count_deg_kernel<<<(E + 255) / 256, 256, 0, stream>>>(ei, ew, cnt, deg, E);
        scan1_kernel<<<nb, 256, 0, stream>>>(cnt, start_local, blockSums, N);
        scan2_kernel<<<1, 512, 0, stream>>>(blockSums, nb);
        scan3_kernel<<<nb, 256, 0, stream>>>(start_local, blockSums, row_start, cursor, deg, N);
        csr_fill_kernel<<<(E + 255) / 256, 256, 0, stream>>>(ei, ew, deg, cursor, csr, E);

        gather_gemm_ln_kernel<<<(N + TR - 1) / TR, 256, 0, stream>>>(
            csr, row_start, cursor, x, W, b, gamma, beta, out, N);
    } else {
        // fallback: atomic scatter + separate gemm_ln (needs only N floats of ws)
        float* deg = (float*)d_ws;
        int n4 = N * DIM / 4;
        fill_zero4<<<(n4 + 255) / 256, 256, 0, stream>>>((float4*)out, n4);
        fill_zero<<<nb, 256, 0, stream>>>(deg, N);
        deg_kernel<<<(E + 255) / 256, 256, 0, stream>>>(ei, ew, deg, E);
        dinv_kernel<<<nb, 256, 0, stream>>>(deg, N);
        long long sthreads = (long long)E * 32;
        scatter_kernel<<<(int)((sthreads + 255) / 256), 256, 0, stream>>>(ei, ew, deg, x, out, E);
        gemm_ln_kernel<<<(N + TR - 1) / TR, 256, 0, stream>>>(x, W, b, gamma, beta, out, N);
    }
}

// Round 6
// 307.216 us; speedup vs baseline: 3.9948x; 1.0051x over previous
//
#include <hip/hip_runtime.h>
#include <math.h>

#define DIM 128
#define TR 32         // nodes per fused block
#define SA_STRIDE 136 // bf16 elements per sA row (128 + 8 pad, keeps 16B alignment)

typedef __attribute__((ext_vector_type(8))) short bf16x8;
typedef __attribute__((ext_vector_type(4))) float f32x4;

__device__ __forceinline__ ushort f2bf(float f) {
    union { float f; unsigned u; } v; v.f = f;
    unsigned u = v.u;
    return (ushort)((u + 0x7FFFu + ((u >> 16) & 1u)) >> 16);  // RNE
}

__global__ void fill_zero(float* p, int n) {
    int i = blockIdx.x * blockDim.x + threadIdx.x;
    if (i < n) p[i] = 0.f;
}

__global__ void fill_zero4(float4* p, int n4) {
    int i = blockIdx.x * blockDim.x + threadIdx.x;
    if (i < n4) p[i] = make_float4(0.f, 0.f, 0.f, 0.f);
}

// Wt[n][k] = bf16(W[k][n]) — 128x128, one-time transpose+convert into ws
__global__ void wt_kernel(const float* __restrict__ W, ushort* __restrict__ Wt) {
    int i = blockIdx.x * blockDim.x + threadIdx.x;  // 16384 threads
    int k = i >> 7, n = i & 127;
    Wt[n * DIM + k] = f2bf(W[k * DIM + n]);
}

// cnt[col]++ ; deg[col] += ew[e]
__global__ void count_deg_kernel(const int* __restrict__ ei, const float* __restrict__ ew,
                                 int* __restrict__ cnt, float* __restrict__ deg, int E) {
    int e = blockIdx.x * blockDim.x + threadIdx.x;
    if (e < E) {
        int col = ei[E + e];
        atomicAdd(&cnt[col], 1);
        atomicAdd(&deg[col], ew[e]);
    }
}

// per-block exclusive scan of cnt -> start_local, blockSums
__global__ __launch_bounds__(256) void scan1_kernel(const int* __restrict__ cnt,
                                                    int* __restrict__ start_local,
                                                    int* __restrict__ blockSums, int N) {
    __shared__ int s[256];
    int t = threadIdx.x;
    int i = blockIdx.x * 256 + t;
    int c = (i < N) ? cnt[i] : 0;
    s[t] = c;
    __syncthreads();
#pragma unroll
    for (int off = 1; off < 256; off <<= 1) {
        int v = (t >= off) ? s[t - off] : 0;
        __syncthreads();
        s[t] += v;
        __syncthreads();
    }
    if (i < N) start_local[i] = s[t] - c;
    if (t == 255) blockSums[blockIdx.x] = s[t];
}

// single-block exclusive scan of blockSums (nb <= 512)
__global__ __launch_bounds__(512) void scan2_kernel(int* __restrict__ blockSums, int nb) {
    __shared__ int s[512];
    int t = threadIdx.x;
    int c = (t < nb) ? blockSums[t] : 0;
    s[t] = c;
    __syncthreads();
#pragma unroll
    for (int off = 1; off < 512; off <<= 1) {
        int v = (t >= off) ? s[t - off] : 0;
        __syncthreads();
        s[t] += v;
        __syncthreads();
    }
    if (t < nb) blockSums[t] = s[t] - c;
}

// row_start/cursor = global prefix; deg -> dinv (fused)
__global__ void scan3_kernel(const int* __restrict__ start_local, const int* __restrict__ blockSums,
                             int* __restrict__ row_start, int* __restrict__ cursor,
                             float* __restrict__ deg, int N) {
    int i = blockIdx.x * blockDim.x + threadIdx.x;
    if (i < N) {
        int rs = start_local[i] + blockSums[i >> 8];
        row_start[i] = rs;
        cursor[i] = rs;
        float d = deg[i];
        deg[i] = d > 0.f ? rsqrtf(d) : 0.f;
    }
}

// CSR fill (packed 8B): p = cursor[col]++; csr[p] = {row, bits(dinv[row]*ew*dinv[col])}
__global__ void csr_fill_kernel(const int* __restrict__ ei, const float* __restrict__ ew,
                                const float* __restrict__ dinv, int* __restrict__ cursor,
                                int2* __restrict__ csr, int E) {
    int e = blockIdx.x * blockDim.x + threadIdx.x;
    if (e < E) {
        int row = ei[e];
        int col = ei[E + e];
        int p = atomicAdd(&cursor[col], 1);
        float w = dinv[row] * ew[e] * dinv[col];
        csr[p] = make_int2(row, __float_as_int(w));
    }
}

// Fused: CSR gather (fp32) -> LDS bf16 -> MFMA 32x128 @ 128x128 -> bias+LN+GELU+residual.
// 256 threads = 4 waves. Gather: 8 groups of 32 lanes, 4 nodes each.
// GEMM: wave w -> row-tile tm=w&1 (16 rows), col-tiles tn = 4*(w>>1)..+3 (64 cols).
// A-frag: one ds_read_b128 per kb; B-frag: one 16B global load from Wt (L1-resident).
__global__ __launch_bounds__(256) void gather_mfma_ln_kernel(
        const int2* __restrict__ csr, const int* __restrict__ row_start,
        const int* __restrict__ seg_end, const float* __restrict__ x,
        const ushort* __restrict__ Wt, const float* __restrict__ b,
        const float* __restrict__ gamma, const float* __restrict__ beta,
        float* __restrict__ out, int N) {
    __shared__ ushort sA[TR * SA_STRIDE];  // 8.5 KB bf16 agg tile
    __shared__ float redS[4][16];
    __shared__ float redQ[4][16];

    const int tid  = threadIdx.x;
    const int l32  = tid & 31;
    const int g32  = tid >> 5;       // gather group 0..7
    const int lane = tid & 63;
    const int w    = tid >> 6;       // wave 0..3
    const int row0 = blockIdx.x * TR;

    // ---- Phase A: gather 4 nodes per 32-lane group, write bf16 to LDS ----
    const float4* xv = (const float4*)x;
#pragma unroll
    for (int q = 0; q < 4; ++q) {
        int r = g32 * 4 + q;
        int node = row0 + r;
        float4 acc = make_float4(0.f, 0.f, 0.f, 0.f);
        if (node < N) {
            int s = row_start[node];
            int e = seg_end[node];
            for (int j = s; j < e; ++j) {
                int2 pk = csr[j];                       // broadcast within group
                float wt = __int_as_float(pk.y);
                float4 v = xv[(size_t)pk.x * 32 + l32];
                acc.x += wt * v.x; acc.y += wt * v.y; acc.z += wt * v.z; acc.w += wt * v.w;
            }
        }
        ushort4 p4;
        p4.x = f2bf(acc.x); p4.y = f2bf(acc.y); p4.z = f2bf(acc.z); p4.w = f2bf(acc.w);
        *(ushort4*)&sA[r * SA_STRIDE + l32 * 4] = p4;   // ds_write_b64, conflict-free
    }
    __syncthreads();

    // ---- Phase B: MFMA GEMM ----
    const int m16  = lane & 15;
    const int quad = lane >> 4;          // 0..3
    const int tm   = w & 1;              // row-tile
    const int tnb  = (w >> 1) * 4;       // first col-tile

    bf16x8 afrag[4];
    const ushort* arow = &sA[(16 * tm + m16) * SA_STRIDE + quad * 8];
#pragma unroll
    for (int kb = 0; kb < 4; ++kb)
        afrag[kb] = *(const bf16x8*)(arow + kb * 32);   // ds_read_b128

    f32x4 acc[4];
#pragma unroll
    for (int t = 0; t < 4; ++t) { acc[t][0] = 0.f; acc[t][1] = 0.f; acc[t][2] = 0.f; acc[t][3] = 0.f; }

#pragma unroll
    for (int kb = 0; kb < 4; ++kb) {
#pragma unroll
        for (int t = 0; t < 4; ++t) {
            const ushort* bp = Wt + (size_t)((tnb + t) * 16 + m16) * DIM + kb * 32 + quad * 8;
            bf16x8 bfrag = *(const bf16x8*)bp;          // global 16B, L1-resident
            acc[t] = __builtin_amdgcn_mfma_f32_16x16x32_bf16(afrag[kb], bfrag, acc[t], 0, 0, 0);
        }
    }

    // ---- bias (per col) before LN stats ----
    float gcol[4], becol[4];
#pragma unroll
    for (int t = 0; t < 4; ++t) {
        int col = (tnb + t) * 16 + m16;
        float bc = b[col];
        gcol[t]  = gamma[col];
        becol[t] = beta[col];
#pragma unroll
        for (int i = 0; i < 4; ++i) acc[t][i] += bc;
    }

    // ---- LN stats: rows 4*quad+i; reduce over this wave's 64 cols via quad shuffles ----
    float s[4], sq[4];
#pragma unroll
    for (int i = 0; i < 4; ++i) {
        s[i]  = acc[0][i] + acc[1][i] + acc[2][i] + acc[3][i];
        sq[i] = acc[0][i]*acc[0][i] + acc[1][i]*acc[1][i] + acc[2][i]*acc[2][i] + acc[3][i]*acc[3][i];
    }
#pragma unroll
    for (int off = 1; off <= 8; off <<= 1) {
#pragma unroll
        for (int i = 0; i < 4; ++i) {
            s[i]  += __shfl_xor(s[i], off);
            sq[i] += __shfl_xor(sq[i], off);
        }
    }
    if (m16 == 0) {
#pragma unroll
        for (int i = 0; i < 4; ++i) {
            redS[w][quad * 4 + i] = s[i];
            redQ[w][quad * 4 + i] = sq[i];
        }
    }
    __syncthreads();

    // ---- finish LN + GELU + residual, store ----
#pragma unroll
    for (int i = 0; i < 4; ++i) {
        int rloc = quad * 4 + i;
        float tot  = redS[w][rloc] + redS[w ^ 2][rloc];   // partner wave shares tm
        float totq = redQ[w][rloc] + redQ[w ^ 2][rloc];
        float mu   = tot * (1.0f / DIM);
        float var  = totq * (1.0f / DIM) - mu * mu;
        float rstd = rsqrtf(var + 1e-5f);
        int r = row0 + 16 * tm + rloc;
        if (r < N) {
#pragma unroll
            for (int t = 0; t < 4; ++t) {
                int col = (tnb + t) * 16 + m16;
                float l = (acc[t][i] - mu) * rstd * gcol[t] + becol[t];
                float g = 0.5f * l * (1.0f + erff(l * 0.70710678118654752f));
                out[(size_t)r * DIM + col] = x[(size_t)r * DIM + col] + g;
            }
        }
    }
}

// ---------------- fallback path (small workspace): atomic scatter + fp32 gemm_ln ----------------
__global__ void deg_kernel(const int* __restrict__ ei, const float* __restrict__ ew,
                           float* __restrict__ deg, int E) {
    int e = blockIdx.x * blockDim.x + threadIdx.x;
    if (e < E) atomicAdd(&deg[ei[E + e]], ew[e]);
}

__global__ void dinv_kernel(float* deg, int N) {
    int i = blockIdx.x * blockDim.x + threadIdx.x;
    if (i < N) {
        float d = deg[i];
        deg[i] = d > 0.f ? rsqrtf(d) : 0.f;
    }
}

__global__ void scatter_kernel(const int* __restrict__ ei, const float* __restrict__ ew,
                               const float* __restrict__ dinv, const float* __restrict__ x,
                               float* __restrict__ out, int E) {
    int t = blockIdx.x * blockDim.x + threadIdx.x;
    int e = t >> 5;
    if (e >= E) return;
    int lane = t & 31;
    int row = ei[e];
    int col = ei[E + e];
    float w = dinv[row] * ew[e] * dinv[col];
    float4 v = *(const float4*)(x + (size_t)row * DIM + (lane << 2));
    float* dst = out + (size_t)col * DIM + (lane << 2);
    atomicAdd(dst + 0, v.x * w);
    atomicAdd(dst + 1, v.y * w);
    atomicAdd(dst + 2, v.z * w);
    atomicAdd(dst + 3, v.w * w);
}

__global__ __launch_bounds__(256) void gemm_ln_kernel(const float* __restrict__ x,
                                                      const float* __restrict__ W,
                                                      const float* __restrict__ b,
                                                      const float* __restrict__ gamma,
                                                      const float* __restrict__ beta,
                                                      float* __restrict__ out, int N) {
    __shared__ float sT[DIM][TR + 4];
    const int tid = threadIdx.x;
    const int row0 = blockIdx.x * TR;
    {
        int r = tid >> 3;
        int c0 = (tid & 7) << 4;
        int rr = row0 + r; if (rr > N - 1) rr = N - 1;
        const float4* src = (const float4*)(out + (size_t)rr * DIM + c0);
#pragma unroll
        for (int i = 0; i < 4; ++i) {
            float4 v = src[i];
            int c = c0 + i * 4;
            sT[c + 0][r] = v.x; sT[c + 1][r] = v.y; sT[c + 2][r] = v.z; sT[c + 3][r] = v.w;
        }
    }
    __syncthreads();
    const int tx = tid & 31;
    const int ty = tid >> 5;
    float acc[4][4] = {};
    const float4* Wv = (const float4*)W;
#pragma unroll 4
    for (int k = 0; k < DIM; ++k) {
        float4 wv = Wv[k * 32 + tx];
        float4 a  = *(const float4*)(&sT[k][ty * 4]);
        acc[0][0] += a.x * wv.x; acc[0][1] += a.x * wv.y; acc[0][2] += a.x * wv.z; acc[0][3] += a.x * wv.w;
        acc[1][0] += a.y * wv.x; acc[1][1] += a.y * wv.y; acc[1][2] += a.y * wv.z; acc[1][3] += a.y * wv.w;
        acc[2][0] += a.z * wv.x; acc[2][1] += a.z * wv.y; acc[2][2] += a.z * wv.z; acc[2][3] += a.z * wv.w;
        acc[3][0] += a.w * wv.x; acc[3][1] += a.w * wv.y; acc[3][2] += a.w * wv.z; acc[3][3] += a.w * wv.w;
    }
    float4 b4 = ((const float4*)b)[tx];
#pragma unroll
    for (int i = 0; i < 4; ++i) {
        acc[i][0] += b4.x; acc[i][1] += b4.y; acc[i][2] += b4.z; acc[i][3] += b4.w;
    }
    float4 g4  = ((const float4*)gamma)[tx];
    float4 be4 = ((const float4*)beta)[tx];
#pragma unroll
    for (int i = 0; i < 4; ++i) {
        float s  = acc[i][0] + acc[i][1] + acc[i][2] + acc[i][3];
        float sq = acc[i][0]*acc[i][0] + acc[i][1]*acc[i][1] + acc[i][2]*acc[i][2] + acc[i][3]*acc[i][3];
#pragma unroll
        for (int off = 16; off > 0; off >>= 1) {
            s  += __shfl_xor(s, off);
            sq += __shfl_xor(sq, off);
        }
        float mu   = s * (1.0f / DIM);
        float var  = sq * (1.0f / DIM) - mu * mu;
        float rstd = rsqrtf(var + 1e-5f);
        int r = row0 + ty * 4 + i;
        if (r < N) {
            float4 xr = *(const float4*)(x + (size_t)r * DIM + tx * 4);
            float lg[4] = {g4.x, g4.y, g4.z, g4.w};
            float lb[4] = {be4.x, be4.y, be4.z, be4.w};
            float lx[4] = {xr.x, xr.y, xr.z, xr.w};
            float o[4];
#pragma unroll
            for (int c = 0; c < 4; ++c) {
                float l = (acc[i][c] - mu) * rstd * lg[c] + lb[c];
                float g = 0.5f * l * (1.0f + erff(l * 0.70710678118654752f));
                o[c] = lx[c] + g;
            }
            *(float4*)(out + (size_t)r * DIM + tx * 4) = make_float4(o[0], o[1], o[2], o[3]);
        }
    }
}

extern "C" void kernel_launch(void* const* d_in, const int* in_sizes, int n_in,
                              void* d_out, int out_size, void* d_ws, size_t ws_size,
                              hipStream_t stream) {
    const float* x     = (const float*)d_in[0];
    const int*   ei    = (const int*)d_in[1];    // [2, E] int32
    const float* ew    = (const float*)d_in[2];
    const float* W     = (const float*)d_in[3];
    const float* b     = (const float*)d_in[4];
    const float* gamma = (const float*)d_in[5];
    const float* beta  = (const float*)d_in[6];
    const int N = in_sizes[0] / DIM;
    const int E = in_sizes[2];
    float* out = (float*)d_out;

    const int nb = (N + 255) / 256;

    // ws words: Wt bf16[128*128] (8192 words) | deg[N] | cnt[N] | start_local[N] |
    //           blockSums[512] | row_start[N] | cursor[N] | pad | csr int2[E]
    size_t hdr_words = 8192 + (size_t)5 * N + 512;
    hdr_words = (hdr_words + 1) & ~(size_t)1;
    size_t ws_need = (hdr_words + (size_t)2 * E) * sizeof(float);

    if (ws_size >= ws_need && nb <= 512) {
        ushort* Wt         = (ushort*)d_ws;
        float*  deg        = (float*)d_ws + 8192;
        int*    cnt        = (int*)(deg + N);
        int*    start_local= cnt + N;
        int*    blockSums  = start_local + N;
        int*    row_start  = blockSums + 512;
        int*    cursor     = row_start + N;
        int2*   csr        = (int2*)((float*)d_ws + hdr_words);

        fill_zero<<<(2 * N + 255) / 256, 256, 0, stream>>>(deg, 2 * N);  // deg + cnt
        wt_kernel<<<64, 256, 0, stream>>>(W, Wt);
        count_deg_kernel<<<(E + 255) / 256, 256, 0, stream>>>(ei, ew, cnt, deg, E);
        scan1_kernel<<<nb, 256, 0, stream>>>(cnt, start_local, blockSums, N);
        scan2_kernel<<<1, 512, 0, stream>>>(blockSums, nb);
        scan3_kernel<<<nb, 256, 0, stream>>>(start_local, blockSums, row_start, cursor, deg, N);
        csr_fill_kernel<<<(E + 255) / 256, 256, 0, stream>>>(ei, ew, deg, cursor, csr, E);

        gather_mfma_ln_kernel<<<(N + TR - 1) / TR, 256, 0, stream>>>(
            csr, row_start, cursor, x, Wt, b, gamma, beta, out, N);
    } else {
        float* deg = (float*)d_ws;
        int n4 = N * DIM / 4;
        fill_zero4<<<(n4 + 255) / 256, 256, 0, stream>>>((float4*)out, n4);
        fill_zero<<<nb, 256, 0, stream>>>(deg, N);
        deg_kernel<<<(E + 255) / 256, 256, 0, stream>>>(ei, ew, deg, E);
        dinv_kernel<<<nb, 256, 0, stream>>>(deg, N);
        long long sthreads = (long long)E * 32;
        scatter_kernel<<<(int)((sthreads + 255) / 256), 256, 0, stream>>>(ei, ew, deg, x, out, E);
        gemm_ln_kernel<<<(N + TR - 1) / TR, 256, 0, stream>>>(x, W, b, gamma, beta, out, N);
    }
}